// Round 1
// baseline (518.347 us; speedup 1.0000x reference)
//
#include <hip/hip_runtime.h>

// LIIF ensemble upsample: x(4,64,80,80) f32, coord(4,320,320,2), cell(4,2)
// -> out(4,266,320,320) f32.
// Channels: [0..8) rel_coords (4 ensembles x 2), [8..264) weighted feats
// (4 ensembles x 64 ch), [264..266) cell_map.

constexpr int B_  = 4;
constexpr int C_  = 64;
constexpr int H_  = 80;
constexpr int W_  = 80;
constexpr int HO_ = 320;
constexpr int WO_ = 320;
constexpr int HW_ = HO_ * WO_;          // 102400
constexpr int OC_ = 2 * 4 + C_ * 4 + 2; // 266

__global__ __launch_bounds__(256) void liif_kernel(
    const float* __restrict__ x,
    const float* __restrict__ coord,
    const float* __restrict__ cell,
    float* __restrict__ out)
{
    const int gid = blockIdx.x * 256 + threadIdx.x;   // exactly B_*HW_ threads
    const int b   = gid / HW_;
    const int pix = gid - b * HW_;

    const float2 cc = *reinterpret_cast<const float2*>(coord + (size_t)(b * HW_ + pix) * 2);
    const float cy0 = cc.x;   // coord[...,0] pairs with H (y)
    const float cx0 = cc.y;   // coord[...,1] pairs with W (x)

    const float rx  = 1.0f / (float)H_;   // y-shift magnitude (ref: rx = 1/H)
    const float ry  = 1.0f / (float)W_;   // x-shift magnitude (ref: ry = 1/W)
    const float eps = 1e-6f;
    const float lo  = -1.0f + 1e-6f;
    const float hi  =  1.0f - 1e-6f;

    // ---- y interpolation sets: a=0 -> vx=-1, a=1 -> vx=+1 ----
    int   yi0[2], yi1[2];
    float wy0[2], wy1[2], Sy[2], Ty[2];
#pragma unroll
    for (int a = 0; a < 2; ++a) {
        const float vx = (a == 0) ? -1.0f : 1.0f;
        float cy = cy0 + vx * rx + eps;
        cy = fminf(fmaxf(cy, lo), hi);
        const float iy  = ((cy + 1.0f) * (float)H_ - 1.0f) * 0.5f;
        const float y0f = floorf(iy);
        const float w1  = iy - y0f;
        const float w0  = 1.0f - w1;
        const float y1f = y0f + 1.0f;
        const float m0  = (y0f >= 0.0f && y0f <= (float)(H_ - 1)) ? 1.0f : 0.0f;
        const float m1  = (y1f >= 0.0f && y1f <= (float)(H_ - 1)) ? 1.0f : 0.0f;
        const int y0c = (int)fminf(fmaxf(y0f, 0.0f), (float)(H_ - 1));
        const int y1c = (int)fminf(fmaxf(y1f, 0.0f), (float)(H_ - 1));
        const float w0m = w0 * m0, w1m = w1 * m1;
        // pos_lr ch0 value at row y: (-1 + ry') + (2*ry')*y,  ry' = 1/H
        const float p0 = (-1.0f + rx) + (2.0f * rx) * (float)y0c;
        const float p1 = (-1.0f + rx) + (2.0f * rx) * (float)y1c;
        yi0[a] = y0c; yi1[a] = y1c;
        wy0[a] = w0m; wy1[a] = w1m;
        Sy[a] = p0 * w0m + p1 * w1m;   // sum pos_y * mask * w  over y-corners
        Ty[a] = w0m + w1m;             // sum mask * w          over y-corners
    }

    // ---- x interpolation sets: d=0 -> vy=-1, d=1 -> vy=+1 ----
    int   xi0[2], xi1[2];
    float wx0[2], wx1[2], Sx[2], Tx[2];
#pragma unroll
    for (int d = 0; d < 2; ++d) {
        const float vy = (d == 0) ? -1.0f : 1.0f;
        float cx = cx0 + vy * ry + eps;
        cx = fminf(fmaxf(cx, lo), hi);
        const float ix  = ((cx + 1.0f) * (float)W_ - 1.0f) * 0.5f;
        const float x0f = floorf(ix);
        const float w1  = ix - x0f;
        const float w0  = 1.0f - w1;
        const float x1f = x0f + 1.0f;
        const float m0  = (x0f >= 0.0f && x0f <= (float)(W_ - 1)) ? 1.0f : 0.0f;
        const float m1  = (x1f >= 0.0f && x1f <= (float)(W_ - 1)) ? 1.0f : 0.0f;
        const int x0c = (int)fminf(fmaxf(x0f, 0.0f), (float)(W_ - 1));
        const int x1c = (int)fminf(fmaxf(x1f, 0.0f), (float)(W_ - 1));
        const float w0m = w0 * m0, w1m = w1 * m1;
        const float p0 = (-1.0f + ry) + (2.0f * ry) * (float)x0c;
        const float p1 = (-1.0f + ry) + (2.0f * ry) * (float)x1c;
        xi0[d] = x0c; xi1[d] = x1c;
        wx0[d] = w0m; wx1[d] = w1m;
        Sx[d] = p0 * w0m + p1 * w1m;
        Tx[d] = w0m + w1m;
    }

    // ---- per-ensemble rel / area (ensemble e: a = e>>1 (vx), d = e&1 (vy)) ----
    float area[4], rel0v[4], rel1v[4];
#pragma unroll
    for (int e = 0; e < 4; ++e) {
        const int a = e >> 1, d = e & 1;
        const float old0 = Sy[a] * Tx[d];   // masked-bilinear sample of pos_y
        const float old1 = Sx[d] * Ty[a];   // masked-bilinear sample of pos_x
        const float r0 = (cy0 - old0) * (float)H_;
        const float r1 = (cx0 - old1) * (float)W_;
        rel0v[e] = r0; rel1v[e] = r1;
        area[e] = fabsf(r0 * r1) + 1e-9f;
    }
    const float tot = area[0] + area[1] + area[2] + area[3];
    float wens[4];
#pragma unroll
    for (int e = 0; e < 4; ++e) wens[e] = area[3 - e] / tot;

    float* outp = out + (size_t)b * OC_ * HW_ + pix;

    // rel channels 0..7
#pragma unroll
    for (int e = 0; e < 4; ++e) {
        outp[(size_t)(2 * e + 0) * HW_] = rel0v[e];
        outp[(size_t)(2 * e + 1) * HW_] = rel1v[e];
    }
    // cell channels 264, 265
    outp[(size_t)264 * HW_] = cell[b * 2 + 0] * (float)H_;
    outp[(size_t)265 * HW_] = cell[b * 2 + 1] * (float)W_;

    // ---- feature channels ----
    const float* xb = x + (size_t)b * C_ * H_ * W_;
    int rowoff[2][2];
    rowoff[0][0] = yi0[0] * W_; rowoff[0][1] = yi1[0] * W_;
    rowoff[1][0] = yi0[1] * W_; rowoff[1][1] = yi1[1] * W_;

    // 16 element offsets (corner layout per ensemble)
    int off[4][4];
#pragma unroll
    for (int e = 0; e < 4; ++e) {
        const int a = e >> 1, d = e & 1;
        off[e][0] = rowoff[a][0] + xi0[d];
        off[e][1] = rowoff[a][0] + xi1[d];
        off[e][2] = rowoff[a][1] + xi0[d];
        off[e][3] = rowoff[a][1] + xi1[d];
    }

    float* of = outp + (size_t)8 * HW_;
    const float* xc = xb;
#pragma unroll 2
    for (int c = 0; c < C_; ++c) {
#pragma unroll
        for (int e = 0; e < 4; ++e) {
            const int a = e >> 1, d = e & 1;
            const float v00 = xc[off[e][0]];
            const float v01 = xc[off[e][1]];
            const float v10 = xc[off[e][2]];
            const float v11 = xc[off[e][3]];
            const float s = wy0[a] * (wx0[d] * v00 + wx1[d] * v01)
                          + wy1[a] * (wx0[d] * v10 + wx1[d] * v11);
            of[(size_t)(e * C_ + c) * HW_] = s * wens[e];
        }
        xc += H_ * W_;
    }
}

extern "C" void kernel_launch(void* const* d_in, const int* in_sizes, int n_in,
                              void* d_out, int out_size, void* d_ws, size_t ws_size,
                              hipStream_t stream) {
    const float* x     = (const float*)d_in[0];
    const float* coord = (const float*)d_in[1];
    const float* cell  = (const float*)d_in[2];
    float* out = (float*)d_out;

    const int total  = B_ * HW_;            // 409600
    const int blocks = (total + 255) / 256; // 1600
    hipLaunchKernelGGL(liif_kernel, dim3(blocks), dim3(256), 0, stream,
                       x, coord, cell, out);
}